// Round 1
// baseline (884.644 us; speedup 1.0000x reference)
//
#include <hip/hip_runtime.h>
#include <math.h>

#define EPS 1e-7f

constexpr int Nn = 4, Hh = 1080, Ww = 1920;
constexpr int HW = Hh * Ww;
constexpr int TOTAL = Nn * HW;

constexpr int TW = 32, TH = 32;          // output tile
constexpr int TXN = 60, TYN = 34;        // tiles per image (60*32=1920 exact, 34*32=1088>1080)
constexpr int HALO = 6;
constexpr float NEAR_MAX = 5.0f;         // = HALO-1; |flow|<=5 -> footprint within halo
constexpr int WINW = TW + 2 * HALO;      // 44
constexpr int WINH = TH + 2 * HALO;      // 44
constexpr int WINSZ = WINW * WINH;       // 1936
constexpr int NTILES = Nn * TYN * TXN;   // 8160
constexpr size_t FACC_BYTES = (size_t)TOTAL * 4 * sizeof(float);   // 132.7 MB
constexpr size_t FLAG_BYTES = (size_t)NTILES * sizeof(int);        // ~32.6 KB

// Hardware FP atomics. Default hipcc flags gate atomicAdd(float*) behind a CAS
// loop (unsafe-fp-atomics); unsafeAtomicAdd forces ds_add_f32 /
// global_atomic_add_f32. Workspace is coarse-grained device memory -> safe.
__device__ __forceinline__ void hwAtomicAdd(float* p, float v) {
    unsafeAtomicAdd(p, v);
}

// ---------------- pass 1: rare far sources (|flow|>5) -> global atomic scatter ----------------

__global__ __launch_bounds__(256) void far_scatter(
    const float* __restrict__ tenIn, const float* __restrict__ tenFlow,
    const float* __restrict__ tenMetric, float* __restrict__ facc,
    int* __restrict__ flags, int haveFlags)
{
    int idx = blockIdx.x * 256 + threadIdx.x;
    if (idx >= TOTAL) return;
    int n = idx / HW;
    int p = idx - n * HW;

    float fxv = tenFlow[(n * 2 + 0) * HW + p];
    float fyv = tenFlow[(n * 2 + 1) * HW + p];
    // near (both |f|<=5) or NaN -> handled by gather / skipped
    if (!(fabsf(fxv) > NEAR_MAX || fabsf(fyv) > NEAR_MAX)) return;

    int y = p / Ww;
    int x = p - y * Ww;
    float fx = (float)x + fxv;
    float fy = (float)y + fyv;
    if (!isfinite(fx) || !isfinite(fy)) return;
    if (!(fx > -1.0f && fx < (float)Ww && fy > -1.0f && fy < (float)Hh)) return;

    float m  = expf(tenMetric[n * HW + p]);
    float v0 = tenIn[(n * 3 + 0) * HW + p] * m;
    float v1 = tenIn[(n * 3 + 1) * HW + p] * m;
    float v2 = tenIn[(n * 3 + 2) * HW + p] * m;

    float flx = floorf(fx), fly = floorf(fy);
    int x0 = (int)flx, y0 = (int)fly;
    float wx1 = fx - flx, wx0 = 1.0f - wx1;
    float wy1 = fy - fly, wy0 = 1.0f - wy1;

#define FCORNER(CX, CY, WGT)                                              \
    do {                                                                  \
        int cx_ = (CX), cy_ = (CY);                                       \
        if (cx_ >= 0 && cx_ < Ww && cy_ >= 0 && cy_ < Hh) {               \
            float w_ = (WGT);                                             \
            size_t cell_ = (size_t)n * HW + (size_t)cy_ * Ww + cx_;       \
            float* a_ = facc + cell_ * 4;                                 \
            hwAtomicAdd(a_ + 0, v0 * w_);                                 \
            hwAtomicAdd(a_ + 1, v1 * w_);                                 \
            hwAtomicAdd(a_ + 2, v2 * w_);                                 \
            hwAtomicAdd(a_ + 3, m * w_);                                  \
            if (haveFlags) {                                              \
                int t_ = (n * TYN + cy_ / TH) * TXN + cx_ / TW;           \
                atomicOr(flags + t_, 1);                                  \
            }                                                             \
        }                                                                 \
    } while (0)

    FCORNER(x0,     y0,     wx0 * wy0);
    FCORNER(x0 + 1, y0,     wx1 * wy0);
    FCORNER(x0,     y0 + 1, wx0 * wy1);
    FCORNER(x0 + 1, y0 + 1, wx1 * wy1);
#undef FCORNER
}

// ---------------- pass 2: tile gather, LDS accumulation, fused normalize ----------------

__global__ __launch_bounds__(256) void gather_splat(
    const float* __restrict__ tenIn, const float* __restrict__ tenFlow,
    const float* __restrict__ tenMetric, const float4* __restrict__ facc,
    const int* __restrict__ flags, int dirtyAll, float* __restrict__ out)
{
    // SoA accumulator: accS[c*1024 + cell] to spread LDS banks
    __shared__ float accS[4 * TW * TH];

    const int tx = blockIdx.x, ty = blockIdx.y, n = blockIdx.z;
    const int tX = tx * TW, tY = ty * TH;
    const int tid = threadIdx.x;

    for (int j = tid; j < 4 * TW * TH; j += 256) accS[j] = 0.0f;
    __syncthreads();

    const float* __restrict__ f0 = tenFlow   + (size_t)(n * 2 + 0) * HW;
    const float* __restrict__ f1 = tenFlow   + (size_t)(n * 2 + 1) * HW;
    const float* __restrict__ mp = tenMetric + (size_t)n * HW;
    const float* __restrict__ i0 = tenIn + (size_t)(n * 3 + 0) * HW;
    const float* __restrict__ i1 = tenIn + (size_t)(n * 3 + 1) * HW;
    const float* __restrict__ i2 = tenIn + (size_t)(n * 3 + 2) * HW;

    for (int i = tid; i < WINSZ; i += 256) {
        int wy = i / WINW;
        int wx = i - wy * WINW;
        int sy = tY - HALO + wy;
        int sx = tX - HALO + wx;
        if (sx < 0 || sx >= Ww || sy < 0 || sy >= Hh) continue;
        int p = sy * Ww + sx;

        float fxv = f0[p], fyv = f1[p];
        // near only (NaN fails -> skip; far handled by pass 1)
        if (!(fabsf(fxv) <= NEAR_MAX && fabsf(fyv) <= NEAR_MAX)) continue;

        float fx = (float)sx + fxv;       // in [-5, 1924] -> safe int cast
        float fy = (float)sy + fyv;
        float flx = floorf(fx), fly = floorf(fy);
        int lx0 = (int)flx - tX;          // NW corner, tile-local
        int ly0 = (int)fly - tY;
        // footprint {lx0,lx0+1}x{ly0,ly0+1} must intersect [0,TW)x[0,TH)
        if (lx0 < -1 || lx0 > TW - 1 || ly0 < -1 || ly0 > TH - 1) continue;

        float m  = expf(mp[p]);
        float v0 = i0[p] * m;
        float v1 = i1[p] * m;
        float v2 = i2[p] * m;

        float wx1 = fx - flx, wx0 = 1.0f - wx1;
        float wy1 = fy - fly, wy0 = 1.0f - wy1;

#define LCORNER(LX, LY, WGT)                                              \
    do {                                                                  \
        int lx_ = (LX), ly_ = (LY);                                       \
        if (lx_ >= 0 && lx_ < TW && ly_ >= 0 && ly_ < TH &&               \
            (tY + ly_) < Hh) {                                            \
            float w_ = (WGT);                                             \
            int cell_ = ly_ * TW + lx_;                                   \
            hwAtomicAdd(&accS[cell_],            v0 * w_);                \
            hwAtomicAdd(&accS[1024 + cell_],     v1 * w_);                \
            hwAtomicAdd(&accS[2048 + cell_],     v2 * w_);                \
            hwAtomicAdd(&accS[3072 + cell_],     m * w_);                 \
        }                                                                 \
    } while (0)

        LCORNER(lx0,     ly0,     wx0 * wy0);
        LCORNER(lx0 + 1, ly0,     wx1 * wy0);
        LCORNER(lx0,     ly0 + 1, wx0 * wy1);
        LCORNER(lx0 + 1, ly0 + 1, wx1 * wy1);
#undef LCORNER
    }
    __syncthreads();

    bool dirty = dirtyAll || (flags && (flags[(n * TYN + ty) * TXN + tx] != 0));

    for (int j = tid; j < TW * TH; j += 256) {
        int ly = j / TW;
        int lx = j - ly * TW;
        int gy = tY + ly;
        int gx = tX + lx;
        if (gy >= Hh) continue;
        size_t cell = (size_t)n * HW + (size_t)gy * Ww + gx;

        float a0 = accS[j];
        float a1 = accS[1024 + j];
        float a2 = accS[2048 + j];
        float a3 = accS[3072 + j];
        if (dirty) {
            float4 f = facc[cell];
            a0 += f.x; a1 += f.y; a2 += f.z; a3 += f.w;
        }
        float d = a3 + EPS;
        size_t pix = (size_t)gy * Ww + gx;
        out[((size_t)n * 3 + 0) * HW + pix] = a0 / d;
        out[((size_t)n * 3 + 1) * HW + pix] = a1 / d;
        out[((size_t)n * 3 + 2) * HW + pix] = a2 / d;
    }
}

extern "C" void kernel_launch(void* const* d_in, const int* in_sizes, int n_in,
                              void* d_out, int out_size, void* d_ws, size_t ws_size,
                              hipStream_t stream) {
    const float* tenIn     = (const float*)d_in[0];
    const float* tenFlow   = (const float*)d_in[1];
    const float* tenMetric = (const float*)d_in[2];
    float* out = (float*)d_out;

    float* facc = (float*)d_ws;
    int haveFlags = (ws_size >= FACC_BYTES + FLAG_BYTES) ? 1 : 0;
    int* flags = haveFlags ? (int*)((char*)d_ws + FACC_BYTES) : nullptr;

    // zero far accumulator (+ flags if present) — poison otherwise
    hipMemsetAsync(d_ws, 0, haveFlags ? (FACC_BYTES + FLAG_BYTES) : FACC_BYTES, stream);

    far_scatter<<<(TOTAL + 255) / 256, 256, 0, stream>>>(
        tenIn, tenFlow, tenMetric, facc, flags, haveFlags);

    dim3 grid(TXN, TYN, Nn);
    gather_splat<<<grid, 256, 0, stream>>>(
        tenIn, tenFlow, tenMetric, (const float4*)facc, flags,
        haveFlags ? 0 : 1, out);
}

// Round 2
// 443.867 us; speedup vs baseline: 1.9930x; 1.9930x over previous
//
#include <hip/hip_runtime.h>
#include <math.h>

#define EPS 1e-7f

constexpr int Nn = 4, Hh = 1080, Ww = 1920;
constexpr int HW = Hh * Ww;
constexpr int TOTAL = Nn * HW;

constexpr int TW = 32, TH = 32;          // output tile
constexpr int TXN = 60, TYN = 34;        // 60*32=1920 exact, 34*32=1088>1080
constexpr int REACH = 5;                 // |flow|<=5 handled by gather pass
constexpr float NEAR_MAX = 5.0f;
constexpr int WINW = TW + 2 * REACH;     // 42
constexpr int WINH = TH + 2 * REACH;     // 42
constexpr int WINSZ = WINW * WINH;       // 1764
constexpr int NTILES = Nn * TYN * TXN;   // 8160
constexpr size_t FACC_BYTES = (size_t)TOTAL * 4 * sizeof(float);   // 132.7 MB
constexpr size_t FLAG_BYTES = (size_t)NTILES * sizeof(int);

// Hardware global fp atomic (workspace is coarse-grained device mem -> safe).
__device__ __forceinline__ void hwAtomicAdd(float* p, float v) {
    unsafeAtomicAdd(p, v);
}

// ---------------- pass 1: rare far sources (|flow|>5) -> global atomic scatter ----------------

__global__ __launch_bounds__(256) void far_scatter(
    const float* __restrict__ tenIn, const float* __restrict__ tenFlow,
    const float* __restrict__ tenMetric, float* __restrict__ facc,
    int* __restrict__ flags, int haveFlags)
{
    int idx = blockIdx.x * 256 + threadIdx.x;
    if (idx >= TOTAL) return;
    int n = idx / HW;
    int p = idx - n * HW;

    float fxv = tenFlow[(n * 2 + 0) * HW + p];
    float fyv = tenFlow[(n * 2 + 1) * HW + p];
    if (!(fabsf(fxv) > NEAR_MAX || fabsf(fyv) > NEAR_MAX)) return;  // near or NaN

    int y = p / Ww;
    int x = p - y * Ww;
    float fx = (float)x + fxv;
    float fy = (float)y + fyv;
    if (!isfinite(fx) || !isfinite(fy)) return;
    if (!(fx > -1.0f && fx < (float)Ww && fy > -1.0f && fy < (float)Hh)) return;

    float m  = expf(tenMetric[n * HW + p]);
    float v0 = tenIn[(n * 3 + 0) * HW + p] * m;
    float v1 = tenIn[(n * 3 + 1) * HW + p] * m;
    float v2 = tenIn[(n * 3 + 2) * HW + p] * m;

    float flx = floorf(fx), fly = floorf(fy);
    int x0 = (int)flx, y0 = (int)fly;
    float wx1 = fx - flx, wx0 = 1.0f - wx1;
    float wy1 = fy - fly, wy0 = 1.0f - wy1;

#define FCORNER(CX, CY, WGT)                                              \
    do {                                                                  \
        int cx_ = (CX), cy_ = (CY);                                       \
        if (cx_ >= 0 && cx_ < Ww && cy_ >= 0 && cy_ < Hh) {               \
            float w_ = (WGT);                                             \
            size_t cell_ = (size_t)n * HW + (size_t)cy_ * Ww + cx_;       \
            float* a_ = facc + cell_ * 4;                                 \
            hwAtomicAdd(a_ + 0, v0 * w_);                                 \
            hwAtomicAdd(a_ + 1, v1 * w_);                                 \
            hwAtomicAdd(a_ + 2, v2 * w_);                                 \
            hwAtomicAdd(a_ + 3, m * w_);                                  \
            if (haveFlags) {                                              \
                int t_ = (n * TYN + cy_ / TH) * TXN + cx_ / TW;           \
                atomicOr(flags + t_, 1);                                  \
            }                                                             \
        }                                                                 \
    } while (0)

    FCORNER(x0,     y0,     wx0 * wy0);
    FCORNER(x0 + 1, y0,     wx1 * wy0);
    FCORNER(x0,     y0 + 1, wx0 * wy1);
    FCORNER(x0 + 1, y0 + 1, wx1 * wy1);
#undef FCORNER
}

// ---------------- pass 2: ownership gather — zero atomics ----------------
// Stage window (fx,fy abs targets + premultiplied vals) in LDS; each thread
// owns a 1x4 run of output cells and accumulates privately in registers.

__global__ __launch_bounds__(256) void gather_splat(
    const float* __restrict__ tenIn, const float* __restrict__ tenFlow,
    const float* __restrict__ tenMetric, const float4* __restrict__ facc,
    const int* __restrict__ flags, int dirtyAll, float* __restrict__ out)
{
    __shared__ float2 sFlow[WINSZ];   // absolute splat target (or sentinel)
    __shared__ float4 sVal[WINSZ];    // (v0*m, v1*m, v2*m, m)

    const int tx = blockIdx.x, ty = blockIdx.y, n = blockIdx.z;
    const int tX = tx * TW, tY = ty * TH;
    const int tid = threadIdx.x;

    const float* __restrict__ f0 = tenFlow   + (size_t)(n * 2 + 0) * HW;
    const float* __restrict__ f1 = tenFlow   + (size_t)(n * 2 + 1) * HW;
    const float* __restrict__ mp = tenMetric + (size_t)n * HW;
    const float* __restrict__ i0 = tenIn + (size_t)(n * 3 + 0) * HW;
    const float* __restrict__ i1 = tenIn + (size_t)(n * 3 + 1) * HW;
    const float* __restrict__ i2 = tenIn + (size_t)(n * 3 + 2) * HW;

    // ---- stage window ----
    for (int i = tid; i < WINSZ; i += 256) {
        int wy = i / WINW;
        int wx = i - wy * WINW;
        int sy = tY - REACH + wy;
        int sx = tX - REACH + wx;
        float2 fl = make_float2(-1.0e30f, -1.0e30f);   // sentinel: never hits
        float4 vv = make_float4(0.0f, 0.0f, 0.0f, 0.0f);
        if (sx >= 0 && sx < Ww && sy >= 0 && sy < Hh) {
            int p = sy * Ww + sx;
            float fxv = f0[p], fyv = f1[p];
            float mr  = mp[p];
            float a0 = i0[p], a1 = i1[p], a2 = i2[p];   // unconditional: full ILP
            if (fabsf(fxv) <= NEAR_MAX && fabsf(fyv) <= NEAR_MAX) {  // NaN fails
                float m = expf(mr);
                fl = make_float2((float)sx + fxv, (float)sy + fyv);
                vv = make_float4(a0 * m, a1 * m, a2 * m, m);
            }
        }
        sFlow[i] = fl;
        sVal[i]  = vv;
    }
    __syncthreads();

    // ---- ownership scan: thread owns cells (r, c0..c0+3) ----
    const int r  = tid >> 3;         // 0..31
    const int g  = tid & 7;          // 0..7
    const int c0 = g * 4;            // local col of first owned cell

    float4 acc0 = make_float4(0.f, 0.f, 0.f, 0.f);
    float4 acc1 = make_float4(0.f, 0.f, 0.f, 0.f);
    float4 acc2 = make_float4(0.f, 0.f, 0.f, 0.f);
    float4 acc3 = make_float4(0.f, 0.f, 0.f, 0.f);

    const float cyf  = (float)(tY + r);
    const float cx0f = (float)(tX + c0);

    // candidate sources: sy in [cy-5, cy+5]  -> wy = r + dy, dy in [0,10]
    //                    sx in [cx0-5, cx0+8] -> wx = c0 + dx, dx in [0,13]
    for (int dy = 0; dy < 2 * REACH + 1; ++dy) {
        const int wrow = (r + dy) * WINW + c0;
        const float2* __restrict__ rowF = sFlow + wrow;
        const float4* __restrict__ rowV = sVal  + wrow;
#pragma unroll
        for (int dx = 0; dx < 14; ++dx) {
            float2 fl = rowF[dx];
            float ay  = 1.0f - fabsf(fl.y - cyf);
            float dxf = fl.x - cx0f;
            if (ay > 0.0f && dxf > -1.0f && dxf < 4.0f) {
                float4 v  = rowV[dx];
                float ax0 = fmaxf(0.0f, 1.0f - fabsf(dxf));
                float ax1 = fmaxf(0.0f, 1.0f - fabsf(dxf - 1.0f));
                float ax2 = fmaxf(0.0f, 1.0f - fabsf(dxf - 2.0f));
                float ax3 = fmaxf(0.0f, 1.0f - fabsf(dxf - 3.0f));
                float w0 = ay * ax0, w1 = ay * ax1, w2 = ay * ax2, w3 = ay * ax3;
                acc0.x += v.x * w0; acc0.y += v.y * w0; acc0.z += v.z * w0; acc0.w += v.w * w0;
                acc1.x += v.x * w1; acc1.y += v.y * w1; acc1.z += v.z * w1; acc1.w += v.w * w1;
                acc2.x += v.x * w2; acc2.y += v.y * w2; acc2.z += v.z * w2; acc2.w += v.w * w2;
                acc3.x += v.x * w3; acc3.y += v.y * w3; acc3.z += v.z * w3; acc3.w += v.w * w3;
            }
        }
    }

    // ---- merge far accumulator + normalize + write ----
    const int gy = tY + r;
    if (gy >= Hh) return;

    const bool dirty = dirtyAll || (flags && (flags[(n * TYN + ty) * TXN + tx] != 0));
    const int gx = tX + c0;
    const size_t cellBase = (size_t)n * HW + (size_t)gy * Ww + gx;

    if (dirty) {
        float4 fA = facc[cellBase + 0];
        float4 fB = facc[cellBase + 1];
        float4 fC = facc[cellBase + 2];
        float4 fD = facc[cellBase + 3];
        acc0.x += fA.x; acc0.y += fA.y; acc0.z += fA.z; acc0.w += fA.w;
        acc1.x += fB.x; acc1.y += fB.y; acc1.z += fB.z; acc1.w += fB.w;
        acc2.x += fC.x; acc2.y += fC.y; acc2.z += fC.z; acc2.w += fC.w;
        acc3.x += fD.x; acc3.y += fD.y; acc3.z += fD.z; acc3.w += fD.w;
    }

    const float inv0 = 1.0f / (acc0.w + EPS);
    const float inv1 = 1.0f / (acc1.w + EPS);
    const float inv2 = 1.0f / (acc2.w + EPS);
    const float inv3 = 1.0f / (acc3.w + EPS);

    const size_t pix = (size_t)gy * Ww + gx;        // gx % 4 == 0 -> 16B aligned
    float4 o;
    o = make_float4(acc0.x * inv0, acc1.x * inv1, acc2.x * inv2, acc3.x * inv3);
    *(float4*)(out + ((size_t)n * 3 + 0) * HW + pix) = o;
    o = make_float4(acc0.y * inv0, acc1.y * inv1, acc2.y * inv2, acc3.y * inv3);
    *(float4*)(out + ((size_t)n * 3 + 1) * HW + pix) = o;
    o = make_float4(acc0.z * inv0, acc1.z * inv1, acc2.z * inv2, acc3.z * inv3);
    *(float4*)(out + ((size_t)n * 3 + 2) * HW + pix) = o;
}

extern "C" void kernel_launch(void* const* d_in, const int* in_sizes, int n_in,
                              void* d_out, int out_size, void* d_ws, size_t ws_size,
                              hipStream_t stream) {
    const float* tenIn     = (const float*)d_in[0];
    const float* tenFlow   = (const float*)d_in[1];
    const float* tenMetric = (const float*)d_in[2];
    float* out = (float*)d_out;

    float* facc = (float*)d_ws;
    int haveFlags = (ws_size >= FACC_BYTES + FLAG_BYTES) ? 1 : 0;
    int* flags = haveFlags ? (int*)((char*)d_ws + FACC_BYTES) : nullptr;

    hipMemsetAsync(d_ws, 0, haveFlags ? (FACC_BYTES + FLAG_BYTES) : FACC_BYTES, stream);

    far_scatter<<<(TOTAL + 255) / 256, 256, 0, stream>>>(
        tenIn, tenFlow, tenMetric, facc, flags, haveFlags);

    dim3 grid(TXN, TYN, Nn);
    gather_splat<<<grid, 256, 0, stream>>>(
        tenIn, tenFlow, tenMetric, (const float4*)facc, flags,
        haveFlags ? 0 : 1, out);
}

// Round 3
// 342.979 us; speedup vs baseline: 2.5793x; 1.2942x over previous
//
#include <hip/hip_runtime.h>
#include <math.h>

#define EPS 1e-7f

constexpr int Nn = 4, Hh = 1080, Ww = 1920;
constexpr int HW = Hh * Ww;
constexpr int TOTAL = Nn * HW;

constexpr int TW = 32, TH = 32;          // output tile
constexpr int TXN = 60, TYN = 34;        // 60*32=1920 exact, 34*32=1088>1080
constexpr int REACH = 5;                 // |flow|<=5 handled by gather pass
constexpr float NEAR_MAX = 5.0f;
constexpr int WINW = TW + 2 * REACH;     // 42
constexpr int WINH = TH + 2 * REACH;     // 42
constexpr int WINSZ = WINW * WINH;       // 1764
constexpr int NITER = (WINSZ + 255) / 256;   // 7
constexpr int NCW = TW + 1;              // 33 NW-cell cols (lx0 in [-1,31])
constexpr int NCH = TH + 1;              // 33 NW-cell rows
constexpr int NCELLS = NCW * NCH;        // 1089
constexpr int CNT_PAD = 1280;            // 256*5 >= NCELLS+1

// ---------------- pass 1: rare far sources (|flow|>5) -> compact global list ----------------
// Flow ~ N(0,1): P(|f|>5) ~ 1e-6 -> ~10 entries. Replaces the 132.7MB facc
// accumulator + full memset with a 64B memset.

__global__ __launch_bounds__(256) void far_scatter(
    const float* __restrict__ tenIn, const float* __restrict__ tenFlow,
    const float* __restrict__ tenMetric,
    unsigned int* __restrict__ farCount, float* __restrict__ farList,
    unsigned int farCap)
{
    int idx = blockIdx.x * 256 + threadIdx.x;
    if (idx >= TOTAL) return;
    int n = idx / HW;
    int p = idx - n * HW;

    float fxv = tenFlow[(n * 2 + 0) * HW + p];
    float fyv = tenFlow[(n * 2 + 1) * HW + p];
    if (!(fabsf(fxv) > NEAR_MAX || fabsf(fyv) > NEAR_MAX)) return;  // near or NaN

    int y = p / Ww;
    int x = p - y * Ww;
    float fx = (float)x + fxv;
    float fy = (float)y + fyv;
    if (!isfinite(fx) || !isfinite(fy)) return;
    if (!(fx > -1.0f && fx < (float)Ww && fy > -1.0f && fy < (float)Hh)) return;

    float m  = expf(tenMetric[n * HW + p]);
    float v0 = tenIn[(n * 3 + 0) * HW + p] * m;
    float v1 = tenIn[(n * 3 + 1) * HW + p] * m;
    float v2 = tenIn[(n * 3 + 2) * HW + p] * m;

    unsigned int slot = atomicAdd(farCount, 1u);
    if (slot < farCap) {
        float* ep = farList + (size_t)slot * 8;
        ep[0] = __int_as_float(n);
        ep[1] = fx;
        ep[2] = fy;
        ep[3] = v0;
        ep[4] = v1;
        ep[5] = v2;
        ep[6] = m;
        ep[7] = 0.0f;
    }
}

// ---------------- pass 2: CSR-bucketed gather ----------------
// Bucket window sources by target NW cell (33x33 incl -1 halo), CSR via
// ds_add_rtn counts + block prefix sum. Each thread owns a 1x4 run and reads
// exactly the 2 contiguous ranges (NW rows r-1, r x 5 cols) that can hit it:
// ~10 candidates at 100% hit rate vs 154 at 6.5%.

__global__ __launch_bounds__(256, 3) void gather_splat(
    const float* __restrict__ tenIn, const float* __restrict__ tenFlow,
    const float* __restrict__ tenMetric,
    const float* __restrict__ farList, const unsigned int* __restrict__ farCount,
    unsigned int farCap, float* __restrict__ out)
{
    __shared__ float2 sFrac[WINSZ];          // (fx_abs, wy1) per CSR slot
    __shared__ float4 sVal[WINSZ];           // (v0*m, v1*m, v2*m, m)
    __shared__ unsigned int sOff[CNT_PAD];   // counts -> CSR offsets (in place)
    __shared__ unsigned int sWsum[8];

    const int tx = blockIdx.x, ty = blockIdx.y, n = blockIdx.z;
    const int tX = tx * TW, tY = ty * TH;
    const int tid = threadIdx.x;

    for (int j = tid; j < CNT_PAD; j += 256) sOff[j] = 0u;
    __syncthreads();

    const float* __restrict__ f0 = tenFlow   + (size_t)(n * 2 + 0) * HW;
    const float* __restrict__ f1 = tenFlow   + (size_t)(n * 2 + 1) * HW;
    const float* __restrict__ mp = tenMetric + (size_t)n * HW;
    const float* __restrict__ i0 = tenIn + (size_t)(n * 3 + 0) * HW;
    const float* __restrict__ i1 = tenIn + (size_t)(n * 3 + 1) * HW;
    const float* __restrict__ i2 = tenIn + (size_t)(n * 3 + 2) * HW;

    // ---- phase 1: load window, count per NW cell, stash in regs ----
    unsigned int pk[NITER];                  // sic<<16 | ci ; 0xFFFFFFFF = invalid
    float sfx[NITER], swy[NITER], sv0[NITER], sv1[NITER], sv2[NITER], smm[NITER];
#pragma unroll
    for (int it = 0; it < NITER; ++it) {
        int i = tid + it * 256;
        unsigned int p_ = 0xFFFFFFFFu;
        float fx = 0.f, wy1 = 0.f, v0 = 0.f, v1 = 0.f, v2 = 0.f, m = 0.f;
        if (i < WINSZ) {
            int wy = i / WINW;
            int wx = i - wy * WINW;
            int sy = tY - REACH + wy;
            int sx = tX - REACH + wx;
            if (sx >= 0 && sx < Ww && sy >= 0 && sy < Hh) {
                int p = sy * Ww + sx;
                float fxv = f0[p], fyv = f1[p];
                float mr  = mp[p];
                float a0 = i0[p], a1 = i1[p], a2 = i2[p];  // unconditional: ILP
                if (fabsf(fxv) <= NEAR_MAX && fabsf(fyv) <= NEAR_MAX) {  // NaN fails
                    fx = (float)sx + fxv;
                    float fy = (float)sy + fyv;
                    float flx = floorf(fx), fly = floorf(fy);
                    int lx0 = (int)flx - tX;
                    int ly0 = (int)fly - tY;
                    if (lx0 >= -1 && lx0 < TW && ly0 >= -1 && ly0 < TH) {
                        int ci = (ly0 + 1) * NCW + (lx0 + 1);
                        unsigned int sic = atomicAdd(&sOff[ci], 1u);  // ds_add_rtn_u32
                        p_  = (sic << 16) | (unsigned int)ci;
                        wy1 = fy - fly;
                        m   = expf(mr);
                        v0 = a0 * m; v1 = a1 * m; v2 = a2 * m;
                    }
                }
            }
        }
        pk[it] = p_; sfx[it] = fx; swy[it] = wy1;
        sv0[it] = v0; sv1[it] = v1; sv2[it] = v2; smm[it] = m;
    }
    __syncthreads();

    // ---- phase 2: exclusive prefix sum over sOff[0..NCELLS] (in place) ----
    unsigned int c0v, c1v, c2v, c3v, c4v;
    {
        int base = tid * 5;
        c0v = sOff[base];     c1v = sOff[base + 1]; c2v = sOff[base + 2];
        c3v = sOff[base + 3]; c4v = sOff[base + 4];
    }
    unsigned int tsum = c0v + c1v + c2v + c3v + c4v;
    unsigned int incl = tsum;
#pragma unroll
    for (int d = 1; d < 64; d <<= 1) {
        unsigned int v = __shfl_up(incl, d);
        if ((tid & 63) >= d) incl += v;
    }
    const int wv = tid >> 6;
    if ((tid & 63) == 63) sWsum[wv] = incl;
    __syncthreads();                 // orders all count-reads before off-writes too
    unsigned int woff = 0;
    {
        unsigned int w0 = sWsum[0], w1 = sWsum[1], w2 = sWsum[2];
        if (wv > 0) woff += w0;
        if (wv > 1) woff += w1;
        if (wv > 2) woff += w2;
    }
    unsigned int texcl = woff + incl - tsum;
    {
        int base = tid * 5;
        unsigned int o0 = texcl, o1 = o0 + c0v, o2 = o1 + c1v, o3 = o2 + c2v, o4 = o3 + c3v;
        sOff[base] = o0; sOff[base + 1] = o1; sOff[base + 2] = o2;
        sOff[base + 3] = o3; sOff[base + 4] = o4;
    }
    __syncthreads();

    // ---- phase 3: scatter into CSR slots ----
#pragma unroll
    for (int it = 0; it < NITER; ++it) {
        unsigned int p_ = pk[it];
        if (p_ != 0xFFFFFFFFu) {
            unsigned int ci  = p_ & 0xFFFFu;
            unsigned int sic = p_ >> 16;
            unsigned int slot = sOff[ci] + sic;
            sFrac[slot] = make_float2(sfx[it], swy[it]);
            sVal[slot]  = make_float4(sv0[it], sv1[it], sv2[it], smm[it]);
        }
    }
    __syncthreads();

    // ---- phase 4: per-thread scan of its 2 CSR ranges ----
    const int r   = tid >> 3;        // 0..31 output row
    const int g   = tid & 7;
    const int cc0 = g * 4;           // first owned col
    const float cx0f = (float)(tX + cc0);

    float4 acc0 = make_float4(0.f, 0.f, 0.f, 0.f);
    float4 acc1 = make_float4(0.f, 0.f, 0.f, 0.f);
    float4 acc2 = make_float4(0.f, 0.f, 0.f, 0.f);
    float4 acc3 = make_float4(0.f, 0.f, 0.f, 0.f);

    // rangeA: NW row = r-1 (cell-row r)   -> row weight = wy1
    // rangeB: NW row = r   (cell-row r+1) -> row weight = 1-wy1
    const unsigned int a0 = sOff[r * NCW + cc0];
    const unsigned int a1 = sOff[r * NCW + cc0 + 5];
    const unsigned int b0 = sOff[(r + 1) * NCW + cc0];
    const unsigned int b1 = sOff[(r + 1) * NCW + cc0 + 5];

#define SPLAT_BODY(AY_EXPR)                                               \
    do {                                                                  \
        float2 fr = sFrac[s];                                             \
        float4 v  = sVal[s];                                              \
        float ay  = (AY_EXPR);                                            \
        float dxf = fr.x - cx0f;                                          \
        float ax0 = fmaxf(0.f, 1.f - fabsf(dxf));                         \
        float ax1 = fmaxf(0.f, 1.f - fabsf(dxf - 1.f));                   \
        float ax2 = fmaxf(0.f, 1.f - fabsf(dxf - 2.f));                   \
        float ax3 = fmaxf(0.f, 1.f - fabsf(dxf - 3.f));                   \
        float w0 = ay * ax0, w1 = ay * ax1, w2 = ay * ax2, w3 = ay * ax3; \
        acc0.x += v.x * w0; acc0.y += v.y * w0; acc0.z += v.z * w0; acc0.w += v.w * w0; \
        acc1.x += v.x * w1; acc1.y += v.y * w1; acc1.z += v.z * w1; acc1.w += v.w * w1; \
        acc2.x += v.x * w2; acc2.y += v.y * w2; acc2.z += v.z * w2; acc2.w += v.w * w2; \
        acc3.x += v.x * w3; acc3.y += v.y * w3; acc3.z += v.z * w3; acc3.w += v.w * w3; \
    } while (0)

    for (unsigned int s = a0; s < a1; ++s) SPLAT_BODY(fr.y);
    for (unsigned int s = b0; s < b1; ++s) SPLAT_BODY(1.f - fr.y);
#undef SPLAT_BODY

    // ---- epilogue: far-list merge + normalize + write ----
    const int gy = tY + r;
    if (gy >= Hh) return;
    const int gx = tX + cc0;

    unsigned int fc = *farCount;
    if (fc > farCap) fc = farCap;
    const float gyf = (float)gy;
    const float gxf = (float)gx;
    for (unsigned int e = 0; e < fc; ++e) {
        const float* ep = farList + (size_t)e * 8;
        if (__float_as_int(ep[0]) != n) continue;
        float ffx = ep[1], ffy = ep[2];
        float ay = fmaxf(0.f, 1.f - fabsf(ffy - gyf));
        if (ay > 0.f) {
            float fv0 = ep[3], fv1 = ep[4], fv2 = ep[5], fm = ep[6];
            float d = ffx - gxf;
            float ax0 = fmaxf(0.f, 1.f - fabsf(d));
            float ax1 = fmaxf(0.f, 1.f - fabsf(d - 1.f));
            float ax2 = fmaxf(0.f, 1.f - fabsf(d - 2.f));
            float ax3 = fmaxf(0.f, 1.f - fabsf(d - 3.f));
            float w0 = ay * ax0, w1 = ay * ax1, w2 = ay * ax2, w3 = ay * ax3;
            acc0.x += fv0 * w0; acc0.y += fv1 * w0; acc0.z += fv2 * w0; acc0.w += fm * w0;
            acc1.x += fv0 * w1; acc1.y += fv1 * w1; acc1.z += fv2 * w1; acc1.w += fm * w1;
            acc2.x += fv0 * w2; acc2.y += fv1 * w2; acc2.z += fv2 * w2; acc2.w += fm * w2;
            acc3.x += fv0 * w3; acc3.y += fv1 * w3; acc3.z += fv2 * w3; acc3.w += fm * w3;
        }
    }

    const float inv0 = 1.0f / (acc0.w + EPS);
    const float inv1 = 1.0f / (acc1.w + EPS);
    const float inv2 = 1.0f / (acc2.w + EPS);
    const float inv3 = 1.0f / (acc3.w + EPS);

    const size_t pix = (size_t)gy * Ww + gx;   // gx % 4 == 0 -> 16B aligned
    float4 o;
    o = make_float4(acc0.x * inv0, acc1.x * inv1, acc2.x * inv2, acc3.x * inv3);
    *(float4*)(out + ((size_t)n * 3 + 0) * HW + pix) = o;
    o = make_float4(acc0.y * inv0, acc1.y * inv1, acc2.y * inv2, acc3.y * inv3);
    *(float4*)(out + ((size_t)n * 3 + 1) * HW + pix) = o;
    o = make_float4(acc0.z * inv0, acc1.z * inv1, acc2.z * inv2, acc3.z * inv3);
    *(float4*)(out + ((size_t)n * 3 + 2) * HW + pix) = o;
}

extern "C" void kernel_launch(void* const* d_in, const int* in_sizes, int n_in,
                              void* d_out, int out_size, void* d_ws, size_t ws_size,
                              hipStream_t stream) {
    const float* tenIn     = (const float*)d_in[0];
    const float* tenFlow   = (const float*)d_in[1];
    const float* tenMetric = (const float*)d_in[2];
    float* out = (float*)d_out;

    unsigned int* farCount = (unsigned int*)d_ws;
    float* farList = (float*)((char*)d_ws + 64);
    unsigned int farCap = (ws_size > 64) ? (unsigned int)((ws_size - 64) / 32) : 0;

    hipMemsetAsync(d_ws, 0, 64, stream);   // just the counter (was 132.7 MB)

    far_scatter<<<(TOTAL + 255) / 256, 256, 0, stream>>>(
        tenIn, tenFlow, tenMetric, farCount, farList, farCap);

    dim3 grid(TXN, TYN, Nn);
    gather_splat<<<grid, 256, 0, stream>>>(
        tenIn, tenFlow, tenMetric, farList, farCount, farCap, out);
}

// Round 4
// 307.474 us; speedup vs baseline: 2.8771x; 1.1155x over previous
//
#include <hip/hip_runtime.h>
#include <math.h>

#define EPS 1e-7f

constexpr int Nn = 4, Hh = 1080, Ww = 1920;
constexpr int HW = Hh * Ww;
constexpr int TOTAL = Nn * HW;

constexpr int TW = 32, TH = 32;          // output tile
constexpr int TXN = 60, TYN = 34;        // 60*32=1920 exact, 34*32=1088>1080
constexpr int REACH = 5;                 // |flow|<=5 handled by gather pass
constexpr float NEAR_MAX = 5.0f;
constexpr int WINW = TW + 2 * REACH;     // 42
constexpr int WINH = TH + 2 * REACH;     // 42
constexpr int WINSZ = WINW * WINH;       // 1764
constexpr int NCW = TW + 1;              // 33 NW-cell cols (lx0 in [-1,31])
constexpr int NCH = TH + 1;              // 33
constexpr int NCELLS = NCW * NCH;        // 1089
constexpr int CNT_PAD = 1280;            // 256*5 >= NCELLS+1
constexpr int PADL = 8;                  // left pad -> 4-aligned chunks
constexpr int NCHUNK = 12;               // 48-px padded row = 12 float4 chunks
constexpr int TOTCH = NCHUNK * WINH;     // 504 chunks per tile window

// ---------------- pass 1: rare far sources (|flow|>5) -> compact global list ----------------
// Vectorized: 4 px/thread, float4 flow loads, quad-level early reject.

__global__ __launch_bounds__(256) void far_scatter(
    const float* __restrict__ tenIn, const float* __restrict__ tenFlow,
    const float* __restrict__ tenMetric,
    unsigned int* __restrict__ farCount, float* __restrict__ farList,
    unsigned int farCap)
{
    int q = blockIdx.x * 256 + threadIdx.x;     // quad index; TOTAL % 4 == 0
    if (q >= TOTAL / 4) return;
    int n  = q / (HW / 4);
    int p  = (q - n * (HW / 4)) * 4;            // base pixel, row-aligned (Ww%4==0)

    const float* __restrict__ f0 = tenFlow + (size_t)(n * 2 + 0) * HW;
    const float* __restrict__ f1 = f0 + HW;
    float4 fx4 = *(const float4*)(f0 + p);
    float4 fy4 = *(const float4*)(f1 + p);

    // quad-level reject: fmaxf drops NaN (NaN px are skipped by design anyway)
    float mx = fmaxf(fmaxf(fabsf(fx4.x), fabsf(fx4.y)), fmaxf(fabsf(fx4.z), fabsf(fx4.w)));
    float my = fmaxf(fmaxf(fabsf(fy4.x), fabsf(fy4.y)), fmaxf(fabsf(fy4.z), fabsf(fy4.w)));
    if (!(mx > NEAR_MAX || my > NEAR_MAX)) return;

    int y = p / Ww;
    int xbase = p - y * Ww;
    float fxa[4] = {fx4.x, fx4.y, fx4.z, fx4.w};
    float fya[4] = {fy4.x, fy4.y, fy4.z, fy4.w};

#pragma unroll
    for (int k = 0; k < 4; ++k) {
        float fxv = fxa[k], fyv = fya[k];
        if (!(fabsf(fxv) > NEAR_MAX || fabsf(fyv) > NEAR_MAX)) continue;  // near or NaN
        float fx = (float)(xbase + k) + fxv;
        float fy = (float)y + fyv;
        if (!isfinite(fx) || !isfinite(fy)) continue;
        if (!(fx > -1.0f && fx < (float)Ww && fy > -1.0f && fy < (float)Hh)) continue;

        int pp = p + k;
        float m  = expf(tenMetric[(size_t)n * HW + pp]);
        float v0 = tenIn[((size_t)n * 3 + 0) * HW + pp] * m;
        float v1 = tenIn[((size_t)n * 3 + 1) * HW + pp] * m;
        float v2 = tenIn[((size_t)n * 3 + 2) * HW + pp] * m;

        unsigned int slot = atomicAdd(farCount, 1u);
        if (slot < farCap) {
            float* ep = farList + (size_t)slot * 8;
            ep[0] = __int_as_float(n);
            ep[1] = fx; ep[2] = fy;
            ep[3] = v0; ep[4] = v1; ep[5] = v2; ep[6] = m;
            ep[7] = 0.0f;
        }
    }
}

// ---------------- pass 2: CSR-bucketed gather, vectorized staging ----------------

__global__ __launch_bounds__(256, 3) void gather_splat(
    const float* __restrict__ tenIn, const float* __restrict__ tenFlow,
    const float* __restrict__ tenMetric,
    const float* __restrict__ farList, const unsigned int* __restrict__ farCount,
    unsigned int farCap, float* __restrict__ out)
{
    __shared__ float2 sFrac[WINSZ];          // (fx_abs, wy1) per CSR slot
    __shared__ float4 sVal[WINSZ];           // (v0*m, v1*m, v2*m, m)
    __shared__ unsigned int sOff[CNT_PAD];   // counts -> CSR offsets (in place)
    __shared__ unsigned int sWsum[8];

    const int tx = blockIdx.x, ty = blockIdx.y, n = blockIdx.z;
    const int tX = tx * TW, tY = ty * TH;
    const int tid = threadIdx.x;

    for (int j = tid; j < CNT_PAD; j += 256) sOff[j] = 0u;
    __syncthreads();

    const float* __restrict__ f0 = tenFlow   + (size_t)(n * 2 + 0) * HW;
    const float* __restrict__ f1 = tenFlow   + (size_t)(n * 2 + 1) * HW;
    const float* __restrict__ mp = tenMetric + (size_t)n * HW;
    const float* __restrict__ i0 = tenIn + (size_t)(n * 3 + 0) * HW;
    const float* __restrict__ i1 = tenIn + (size_t)(n * 3 + 1) * HW;
    const float* __restrict__ i2 = tenIn + (size_t)(n * 3 + 2) * HW;

    // ---- phase 1: float4 flow loads, bucket-count, stash (fx, wy1) ----
    unsigned int pk[2][4];
    float sfx[2][4], swy[2][4];

#pragma unroll
    for (int cc = 0; cc < 2; ++cc) {
#pragma unroll
        for (int k = 0; k < 4; ++k) { pk[cc][k] = 0xFFFFFFFFu; sfx[cc][k] = 0.f; swy[cc][k] = 0.f; }
        int cidx = tid + cc * 256;
        if (cidx >= TOTCH) continue;
        int wy = cidx / NCHUNK;
        int cx = cidx - wy * NCHUNK;
        int sy = tY - REACH + wy;
        int gx = tX - PADL + cx * 4;              // 4-aligned; chunk fully in or out
        if (sy < 0 || sy >= Hh || gx < 0 || gx > Ww - 4) continue;
        int p = sy * Ww + gx;
        float4 fx4 = *(const float4*)(f0 + p);
        float4 fy4 = *(const float4*)(f1 + p);
        float fxa[4] = {fx4.x, fx4.y, fx4.z, fx4.w};
        float fya[4] = {fy4.x, fy4.y, fy4.z, fy4.w};
#pragma unroll
        for (int k = 0; k < 4; ++k) {
            int x = gx + k;
            if (x < tX - REACH || x >= tX + TW + REACH) continue;  // padding px: exact-excluded
            float fxv = fxa[k], fyv = fya[k];
            if (!(fabsf(fxv) <= NEAR_MAX && fabsf(fyv) <= NEAR_MAX)) continue;  // NaN fails
            float fx = (float)x + fxv;
            float fy = (float)sy + fyv;
            float flx = floorf(fx), fly = floorf(fy);
            int lx0 = (int)flx - tX;
            int ly0 = (int)fly - tY;
            if (lx0 < -1 || lx0 >= TW || ly0 < -1 || ly0 >= TH) continue;
            int ci = (ly0 + 1) * NCW + (lx0 + 1);
            unsigned int sic = atomicAdd(&sOff[ci], 1u);   // ds_add_rtn_u32
            pk[cc][k] = (sic << 16) | (unsigned int)ci;
            sfx[cc][k] = fx;
            swy[cc][k] = fy - fly;
        }
    }
    __syncthreads();

    // ---- phase 2: exclusive prefix sum over sOff (in place) ----
    unsigned int c0v, c1v, c2v, c3v, c4v;
    {
        int base = tid * 5;
        c0v = sOff[base];     c1v = sOff[base + 1]; c2v = sOff[base + 2];
        c3v = sOff[base + 3]; c4v = sOff[base + 4];
    }
    unsigned int tsum = c0v + c1v + c2v + c3v + c4v;
    unsigned int incl = tsum;
#pragma unroll
    for (int d = 1; d < 64; d <<= 1) {
        unsigned int v = __shfl_up(incl, d);
        if ((tid & 63) >= d) incl += v;
    }
    const int wv = tid >> 6;
    if ((tid & 63) == 63) sWsum[wv] = incl;
    __syncthreads();
    unsigned int woff = 0;
    {
        unsigned int w0 = sWsum[0], w1 = sWsum[1], w2 = sWsum[2];
        if (wv > 0) woff += w0;
        if (wv > 1) woff += w1;
        if (wv > 2) woff += w2;
    }
    unsigned int texcl = woff + incl - tsum;
    {
        int base = tid * 5;
        unsigned int o0 = texcl, o1 = o0 + c0v, o2 = o1 + c1v, o3 = o2 + c2v, o4 = o3 + c3v;
        sOff[base] = o0; sOff[base + 1] = o1; sOff[base + 2] = o2;
        sOff[base + 3] = o3; sOff[base + 4] = o4;
    }
    __syncthreads();

    // ---- phase 3: float4 value loads (only bucketed chunks), scatter to CSR ----
#pragma unroll
    for (int cc = 0; cc < 2; ++cc) {
        int cidx = tid + cc * 256;
        if (cidx >= TOTCH) continue;
        unsigned int allv = pk[cc][0] & pk[cc][1] & pk[cc][2] & pk[cc][3];
        if (allv == 0xFFFFFFFFu) continue;        // no bucketed px in chunk
        int wy = cidx / NCHUNK;
        int cx = cidx - wy * NCHUNK;
        int sy = tY - REACH + wy;
        int gx = tX - PADL + cx * 4;              // bucketed => chunk was valid
        int p = sy * Ww + gx;
        float4 m4  = *(const float4*)(mp + p);
        float4 a04 = *(const float4*)(i0 + p);
        float4 a14 = *(const float4*)(i1 + p);
        float4 a24 = *(const float4*)(i2 + p);
        float ma[4]  = {m4.x,  m4.y,  m4.z,  m4.w};
        float a0a[4] = {a04.x, a04.y, a04.z, a04.w};
        float a1a[4] = {a14.x, a14.y, a14.z, a14.w};
        float a2a[4] = {a24.x, a24.y, a24.z, a24.w};
#pragma unroll
        for (int k = 0; k < 4; ++k) {
            unsigned int p_ = pk[cc][k];
            if (p_ == 0xFFFFFFFFu) continue;
            unsigned int ci  = p_ & 0xFFFFu;
            unsigned int sic = p_ >> 16;
            unsigned int slot = sOff[ci] + sic;
            float m = expf(ma[k]);
            sFrac[slot] = make_float2(sfx[cc][k], swy[cc][k]);
            sVal[slot]  = make_float4(a0a[k] * m, a1a[k] * m, a2a[k] * m, m);
        }
    }
    __syncthreads();

    // ---- phase 4: per-thread scan of its 2 CSR ranges ----
    const int r   = tid >> 3;        // 0..31 output row
    const int g   = tid & 7;
    const int cc0 = g * 4;           // first owned col
    const float cx0f = (float)(tX + cc0);

    float4 acc0 = make_float4(0.f, 0.f, 0.f, 0.f);
    float4 acc1 = make_float4(0.f, 0.f, 0.f, 0.f);
    float4 acc2 = make_float4(0.f, 0.f, 0.f, 0.f);
    float4 acc3 = make_float4(0.f, 0.f, 0.f, 0.f);

    const unsigned int a0 = sOff[r * NCW + cc0];
    const unsigned int a1 = sOff[r * NCW + cc0 + 5];
    const unsigned int b0 = sOff[(r + 1) * NCW + cc0];
    const unsigned int b1 = sOff[(r + 1) * NCW + cc0 + 5];

#define SPLAT_BODY(AY_EXPR)                                               \
    do {                                                                  \
        float2 fr = sFrac[s];                                             \
        float4 v  = sVal[s];                                              \
        float ay  = (AY_EXPR);                                            \
        float dxf = fr.x - cx0f;                                          \
        float ax0 = fmaxf(0.f, 1.f - fabsf(dxf));                         \
        float ax1 = fmaxf(0.f, 1.f - fabsf(dxf - 1.f));                   \
        float ax2 = fmaxf(0.f, 1.f - fabsf(dxf - 2.f));                   \
        float ax3 = fmaxf(0.f, 1.f - fabsf(dxf - 3.f));                   \
        float w0 = ay * ax0, w1 = ay * ax1, w2 = ay * ax2, w3 = ay * ax3; \
        acc0.x += v.x * w0; acc0.y += v.y * w0; acc0.z += v.z * w0; acc0.w += v.w * w0; \
        acc1.x += v.x * w1; acc1.y += v.y * w1; acc1.z += v.z * w1; acc1.w += v.w * w1; \
        acc2.x += v.x * w2; acc2.y += v.y * w2; acc2.z += v.z * w2; acc2.w += v.w * w2; \
        acc3.x += v.x * w3; acc3.y += v.y * w3; acc3.z += v.z * w3; acc3.w += v.w * w3; \
    } while (0)

    for (unsigned int s = a0; s < a1; ++s) SPLAT_BODY(fr.y);
    for (unsigned int s = b0; s < b1; ++s) SPLAT_BODY(1.f - fr.y);
#undef SPLAT_BODY

    // ---- epilogue: far-list merge + normalize + write ----
    const int gy = tY + r;
    if (gy >= Hh) return;
    const int gx = tX + cc0;

    unsigned int fc = *farCount;
    if (fc > farCap) fc = farCap;
    const float gyf = (float)gy;
    const float gxf = (float)gx;
    for (unsigned int e = 0; e < fc; ++e) {
        const float* ep = farList + (size_t)e * 8;
        if (__float_as_int(ep[0]) != n) continue;
        float ffx = ep[1], ffy = ep[2];
        float ay = fmaxf(0.f, 1.f - fabsf(ffy - gyf));
        if (ay > 0.f) {
            float fv0 = ep[3], fv1 = ep[4], fv2 = ep[5], fm = ep[6];
            float d = ffx - gxf;
            float ax0 = fmaxf(0.f, 1.f - fabsf(d));
            float ax1 = fmaxf(0.f, 1.f - fabsf(d - 1.f));
            float ax2 = fmaxf(0.f, 1.f - fabsf(d - 2.f));
            float ax3 = fmaxf(0.f, 1.f - fabsf(d - 3.f));
            float w0 = ay * ax0, w1 = ay * ax1, w2 = ay * ax2, w3 = ay * ax3;
            acc0.x += fv0 * w0; acc0.y += fv1 * w0; acc0.z += fv2 * w0; acc0.w += fm * w0;
            acc1.x += fv0 * w1; acc1.y += fv1 * w1; acc1.z += fv2 * w1; acc1.w += fm * w1;
            acc2.x += fv0 * w2; acc2.y += fv1 * w2; acc2.z += fv2 * w2; acc2.w += fm * w2;
            acc3.x += fv0 * w3; acc3.y += fv1 * w3; acc3.z += fv2 * w3; acc3.w += fm * w3;
        }
    }

    const float inv0 = 1.0f / (acc0.w + EPS);
    const float inv1 = 1.0f / (acc1.w + EPS);
    const float inv2 = 1.0f / (acc2.w + EPS);
    const float inv3 = 1.0f / (acc3.w + EPS);

    const size_t pix = (size_t)gy * Ww + gx;   // gx % 4 == 0 -> 16B aligned
    float4 o;
    o = make_float4(acc0.x * inv0, acc1.x * inv1, acc2.x * inv2, acc3.x * inv3);
    *(float4*)(out + ((size_t)n * 3 + 0) * HW + pix) = o;
    o = make_float4(acc0.y * inv0, acc1.y * inv1, acc2.y * inv2, acc3.y * inv3);
    *(float4*)(out + ((size_t)n * 3 + 1) * HW + pix) = o;
    o = make_float4(acc0.z * inv0, acc1.z * inv1, acc2.z * inv2, acc3.z * inv3);
    *(float4*)(out + ((size_t)n * 3 + 2) * HW + pix) = o;
}

extern "C" void kernel_launch(void* const* d_in, const int* in_sizes, int n_in,
                              void* d_out, int out_size, void* d_ws, size_t ws_size,
                              hipStream_t stream) {
    const float* tenIn     = (const float*)d_in[0];
    const float* tenFlow   = (const float*)d_in[1];
    const float* tenMetric = (const float*)d_in[2];
    float* out = (float*)d_out;

    unsigned int* farCount = (unsigned int*)d_ws;
    float* farList = (float*)((char*)d_ws + 64);
    unsigned int farCap = (ws_size > 64) ? (unsigned int)((ws_size - 64) / 32) : 0;

    hipMemsetAsync(d_ws, 0, 64, stream);

    far_scatter<<<(TOTAL / 4 + 255) / 256, 256, 0, stream>>>(
        tenIn, tenFlow, tenMetric, farCount, farList, farCap);

    dim3 grid(TXN, TYN, Nn);
    gather_splat<<<grid, 256, 0, stream>>>(
        tenIn, tenFlow, tenMetric, farList, farCount, farCap, out);
}

// Round 5
// 291.331 us; speedup vs baseline: 3.0366x; 1.0554x over previous
//
#include <hip/hip_runtime.h>
#include <math.h>

#define EPS 1e-7f

constexpr int Nn = 4, Hh = 1080, Ww = 1920;
constexpr int HW = Hh * Ww;
constexpr int TOTAL = Nn * HW;

constexpr int TW = 32, TH = 32;          // output tile
constexpr int TXN = 60, TYN = 34;        // 60*32=1920 exact, 34*32=1088>1080
constexpr int REACH = 5;                 // |flow|<=5 handled by gather pass
constexpr float NEAR_MAX = 5.0f;
constexpr int WINW = TW + 2 * REACH;     // 42
constexpr int WINH = TH + 2 * REACH;     // 42
constexpr int WINSZ = WINW * WINH;       // 1764
constexpr int NCW = TW + 1;              // 33 NW-cell cols (lx0 in [-1,31])
constexpr int NCH = TH + 1;              // 33
constexpr int NCELLS = NCW * NCH;        // 1089
constexpr int NOFF = NCELLS + 1;         // 1090 = 218*5 exactly
constexpr int PADL = 8;                  // left pad -> 4-aligned chunks
constexpr int NCHUNK = 12;               // 48-px padded row = 12 float4 chunks
constexpr int TOTCH = NCHUNK * WINH;     // 504 chunks per tile window
constexpr float INV64K = 1.52587890625e-5f;  // 2^-16

// ---------------- pass 1: rare far sources (|flow|>5) -> compact global list ----------------

__global__ __launch_bounds__(256) void far_scatter(
    const float* __restrict__ tenIn, const float* __restrict__ tenFlow,
    const float* __restrict__ tenMetric,
    unsigned int* __restrict__ farCount, float* __restrict__ farList,
    unsigned int farCap)
{
    int q = blockIdx.x * 256 + threadIdx.x;     // quad index; TOTAL % 4 == 0
    if (q >= TOTAL / 4) return;
    int n  = q / (HW / 4);
    int p  = (q - n * (HW / 4)) * 4;            // base pixel, row-aligned (Ww%4==0)

    const float* __restrict__ f0 = tenFlow + (size_t)(n * 2 + 0) * HW;
    const float* __restrict__ f1 = f0 + HW;
    float4 fx4 = *(const float4*)(f0 + p);
    float4 fy4 = *(const float4*)(f1 + p);

    float mx = fmaxf(fmaxf(fabsf(fx4.x), fabsf(fx4.y)), fmaxf(fabsf(fx4.z), fabsf(fx4.w)));
    float my = fmaxf(fmaxf(fabsf(fy4.x), fabsf(fy4.y)), fmaxf(fabsf(fy4.z), fabsf(fy4.w)));
    if (!(mx > NEAR_MAX || my > NEAR_MAX)) return;

    int y = p / Ww;
    int xbase = p - y * Ww;
    float fxa[4] = {fx4.x, fx4.y, fx4.z, fx4.w};
    float fya[4] = {fy4.x, fy4.y, fy4.z, fy4.w};

#pragma unroll
    for (int k = 0; k < 4; ++k) {
        float fxv = fxa[k], fyv = fya[k];
        if (!(fabsf(fxv) > NEAR_MAX || fabsf(fyv) > NEAR_MAX)) continue;  // near or NaN
        float fx = (float)(xbase + k) + fxv;
        float fy = (float)y + fyv;
        if (!isfinite(fx) || !isfinite(fy)) continue;
        if (!(fx > -1.0f && fx < (float)Ww && fy > -1.0f && fy < (float)Hh)) continue;

        int pp = p + k;
        float m  = expf(tenMetric[(size_t)n * HW + pp]);
        float v0 = tenIn[((size_t)n * 3 + 0) * HW + pp] * m;
        float v1 = tenIn[((size_t)n * 3 + 1) * HW + pp] * m;
        float v2 = tenIn[((size_t)n * 3 + 2) * HW + pp] * m;

        unsigned int slot = atomicAdd(farCount, 1u);
        if (slot < farCap) {
            float* ep = farList + (size_t)slot * 8;
            ep[0] = __int_as_float(n);
            ep[1] = fx; ep[2] = fy;
            ep[3] = v0; ep[4] = v1; ep[5] = v2; ep[6] = m;
            ep[7] = 0.0f;
        }
    }
}

// ---------------- pass 2: CSR-bucketed gather, per-cell walk, 4 blocks/CU ----------------

__global__ __launch_bounds__(256, 4) void gather_splat(
    const float* __restrict__ tenIn, const float* __restrict__ tenFlow,
    const float* __restrict__ tenMetric,
    const float* __restrict__ farList, const unsigned int* __restrict__ farCount,
    unsigned int farCap, float* __restrict__ out)
{
    __shared__ float4 sVal[WINSZ];           // (v0*m, v1*m, v2*m, m)   28224 B
    __shared__ unsigned int sPack[WINSZ];    // fracx | wy1<<16 (16b fx) 7056 B
    __shared__ unsigned int sOff[NOFF];      // counts -> CSR offsets    4360 B
    __shared__ unsigned int sWsum[8];
    // total 39672 B -> 4 blocks/CU

    const int tx = blockIdx.x, ty = blockIdx.y, n = blockIdx.z;
    const int tX = tx * TW, tY = ty * TH;
    const int tid = threadIdx.x;

    for (int j = tid; j < NOFF; j += 256) sOff[j] = 0u;
    __syncthreads();

    const float* __restrict__ f0 = tenFlow   + (size_t)(n * 2 + 0) * HW;
    const float* __restrict__ f1 = tenFlow   + (size_t)(n * 2 + 1) * HW;
    const float* __restrict__ mp = tenMetric + (size_t)n * HW;
    const float* __restrict__ i0 = tenIn + (size_t)(n * 3 + 0) * HW;
    const float* __restrict__ i1 = tenIn + (size_t)(n * 3 + 1) * HW;
    const float* __restrict__ i2 = tenIn + (size_t)(n * 3 + 2) * HW;

    // ---- phase 1: float4 flow loads, bucket-count, stash packed fracs ----
    unsigned int pk[2][4];    // sic<<16 | ci ; 0xFFFFFFFF = invalid
    unsigned int spw[2][4];   // packed (fracx, wy1)

#pragma unroll
    for (int cc = 0; cc < 2; ++cc) {
#pragma unroll
        for (int k = 0; k < 4; ++k) { pk[cc][k] = 0xFFFFFFFFu; spw[cc][k] = 0u; }
        int cidx = tid + cc * 256;
        if (cidx >= TOTCH) continue;
        int wy = cidx / NCHUNK;
        int cx = cidx - wy * NCHUNK;
        int sy = tY - REACH + wy;
        int gx = tX - PADL + cx * 4;              // 4-aligned; chunk fully in or out
        if (sy < 0 || sy >= Hh || gx < 0 || gx > Ww - 4) continue;
        int p = sy * Ww + gx;
        float4 fx4 = *(const float4*)(f0 + p);
        float4 fy4 = *(const float4*)(f1 + p);
        float fxa[4] = {fx4.x, fx4.y, fx4.z, fx4.w};
        float fya[4] = {fy4.x, fy4.y, fy4.z, fy4.w};
#pragma unroll
        for (int k = 0; k < 4; ++k) {
            int x = gx + k;
            if (x < tX - REACH || x >= tX + TW + REACH) continue;  // padding px
            float fxv = fxa[k], fyv = fya[k];
            if (!(fabsf(fxv) <= NEAR_MAX && fabsf(fyv) <= NEAR_MAX)) continue;  // NaN fails
            float fx = (float)x + fxv;
            float fy = (float)sy + fyv;
            float flx = floorf(fx), fly = floorf(fy);
            int lx0 = (int)flx - tX;
            int ly0 = (int)fly - tY;
            if (lx0 < -1 || lx0 >= TW || ly0 < -1 || ly0 >= TH) continue;
            int ci = (ly0 + 1) * NCW + (lx0 + 1);
            unsigned int sic = atomicAdd(&sOff[ci], 1u);   // ds_add_rtn_u32
            pk[cc][k] = (sic << 16) | (unsigned int)ci;
            spw[cc][k] = __float2uint_rz((fx - flx) * 65536.0f)
                       | (__float2uint_rz((fy - fly) * 65536.0f) << 16);
        }
    }
    __syncthreads();

    // ---- phase 2: exclusive prefix sum over sOff[0..NOFF) (218 threads x 5) ----
    unsigned int c0v = 0, c1v = 0, c2v = 0, c3v = 0, c4v = 0;
    if (tid < 218) {
        int base = tid * 5;
        c0v = sOff[base];     c1v = sOff[base + 1]; c2v = sOff[base + 2];
        c3v = sOff[base + 3]; c4v = sOff[base + 4];
    }
    unsigned int tsum = c0v + c1v + c2v + c3v + c4v;
    unsigned int incl = tsum;
#pragma unroll
    for (int d = 1; d < 64; d <<= 1) {
        unsigned int v = __shfl_up(incl, d);
        if ((tid & 63) >= d) incl += v;
    }
    const int wv = tid >> 6;
    if ((tid & 63) == 63) sWsum[wv] = incl;
    __syncthreads();                 // orders count-reads before off-writes too
    unsigned int woff = 0;
    {
        unsigned int w0 = sWsum[0], w1 = sWsum[1], w2 = sWsum[2];
        if (wv > 0) woff += w0;
        if (wv > 1) woff += w1;
        if (wv > 2) woff += w2;
    }
    unsigned int texcl = woff + incl - tsum;
    if (tid < 218) {
        int base = tid * 5;
        unsigned int o0 = texcl, o1 = o0 + c0v, o2 = o1 + c1v, o3 = o2 + c2v, o4 = o3 + c3v;
        sOff[base] = o0; sOff[base + 1] = o1; sOff[base + 2] = o2;
        sOff[base + 3] = o3; sOff[base + 4] = o4;
    }
    __syncthreads();

    // ---- phase 3: float4 value loads (only bucketed chunks), scatter to CSR ----
#pragma unroll
    for (int cc = 0; cc < 2; ++cc) {
        int cidx = tid + cc * 256;
        if (cidx >= TOTCH) continue;
        unsigned int allv = pk[cc][0] & pk[cc][1] & pk[cc][2] & pk[cc][3];
        if (allv == 0xFFFFFFFFu) continue;        // no bucketed px in chunk
        int wy = cidx / NCHUNK;
        int cx = cidx - wy * NCHUNK;
        int sy = tY - REACH + wy;
        int gx = tX - PADL + cx * 4;              // bucketed => chunk was valid
        int p = sy * Ww + gx;
        float4 m4  = *(const float4*)(mp + p);
        float4 a04 = *(const float4*)(i0 + p);
        float4 a14 = *(const float4*)(i1 + p);
        float4 a24 = *(const float4*)(i2 + p);
        float ma[4]  = {m4.x,  m4.y,  m4.z,  m4.w};
        float a0a[4] = {a04.x, a04.y, a04.z, a04.w};
        float a1a[4] = {a14.x, a14.y, a14.z, a14.w};
        float a2a[4] = {a24.x, a24.y, a24.z, a24.w};
#pragma unroll
        for (int k = 0; k < 4; ++k) {
            unsigned int p_ = pk[cc][k];
            if (p_ == 0xFFFFFFFFu) continue;
            unsigned int ci  = p_ & 0xFFFFu;
            unsigned int sic = p_ >> 16;
            unsigned int slot = sOff[ci] + sic;
            float m = expf(ma[k]);
            sPack[slot] = spw[cc][k];
            sVal[slot]  = make_float4(a0a[k] * m, a1a[k] * m, a2a[k] * m, m);
        }
    }
    __syncthreads();

    // ---- phase 4: per-cell walk; each source -> exactly 2 static columns ----
    const int r   = tid >> 3;        // 0..31 output row
    const int g   = tid & 7;
    const int cc0 = g * 4;           // first owned col

    float4 acc0 = make_float4(0.f, 0.f, 0.f, 0.f);
    float4 acc1 = make_float4(0.f, 0.f, 0.f, 0.f);
    float4 acc2 = make_float4(0.f, 0.f, 0.f, 0.f);
    float4 acc3 = make_float4(0.f, 0.f, 0.f, 0.f);

    // cell row r   (ly0=r-1): ay = wy1 ; cell row r+1 (ly0=r): ay = 1-wy1
#define SUBR(S0, S1, ROWA, HASL, HASR, ACCL, ACCR)                        \
    for (unsigned int s = (S0); s < (S1); ++s) {                          \
        unsigned int pw = sPack[s];                                       \
        float4 v = sVal[s];                                               \
        float fracx = (float)(pw & 0xFFFFu) * INV64K;                     \
        float wy1q  = (float)(pw >> 16)     * INV64K;                     \
        float ay = (ROWA) ? wy1q : (1.0f - wy1q);                         \
        float wr = ay * fracx;                                            \
        float wl = ay - wr;                                               \
        if (HASL) { ACCL.x += v.x*wl; ACCL.y += v.y*wl;                   \
                    ACCL.z += v.z*wl; ACCL.w += v.w*wl; }                 \
        if (HASR) { ACCR.x += v.x*wr; ACCR.y += v.y*wr;                   \
                    ACCR.z += v.z*wr; ACCR.w += v.w*wr; }                 \
    }

    {
        const int baseA = r * NCW + cc0;
        unsigned int o0 = sOff[baseA],     o1 = sOff[baseA + 1];
        unsigned int o2 = sOff[baseA + 2], o3 = sOff[baseA + 3];
        unsigned int o4 = sOff[baseA + 4], o5 = sOff[baseA + 5];
        SUBR(o0, o1, true, false, true,  acc0, acc0)   // cell col cc0   -> R:col0
        SUBR(o1, o2, true, true,  true,  acc0, acc1)
        SUBR(o2, o3, true, true,  true,  acc1, acc2)
        SUBR(o3, o4, true, true,  true,  acc2, acc3)
        SUBR(o4, o5, true, true,  false, acc3, acc0)   // cell col cc0+4 -> L:col3
    }
    {
        const int baseB = (r + 1) * NCW + cc0;
        unsigned int o0 = sOff[baseB],     o1 = sOff[baseB + 1];
        unsigned int o2 = sOff[baseB + 2], o3 = sOff[baseB + 3];
        unsigned int o4 = sOff[baseB + 4], o5 = sOff[baseB + 5];
        SUBR(o0, o1, false, false, true,  acc0, acc0)
        SUBR(o1, o2, false, true,  true,  acc0, acc1)
        SUBR(o2, o3, false, true,  true,  acc1, acc2)
        SUBR(o3, o4, false, true,  true,  acc2, acc3)
        SUBR(o4, o5, false, true,  false, acc3, acc0)
    }
#undef SUBR

    // ---- epilogue: far-list merge + normalize + write ----
    const int gy = tY + r;
    if (gy >= Hh) return;
    const int gx = tX + cc0;

    unsigned int fc = *farCount;
    if (fc > farCap) fc = farCap;
    const float gyf = (float)gy;
    const float gxf = (float)gx;
    for (unsigned int e = 0; e < fc; ++e) {
        const float* ep = farList + (size_t)e * 8;
        if (__float_as_int(ep[0]) != n) continue;
        float ffx = ep[1], ffy = ep[2];
        float ay = fmaxf(0.f, 1.f - fabsf(ffy - gyf));
        if (ay > 0.f) {
            float fv0 = ep[3], fv1 = ep[4], fv2 = ep[5], fm = ep[6];
            float d = ffx - gxf;
            float ax0 = fmaxf(0.f, 1.f - fabsf(d));
            float ax1 = fmaxf(0.f, 1.f - fabsf(d - 1.f));
            float ax2 = fmaxf(0.f, 1.f - fabsf(d - 2.f));
            float ax3 = fmaxf(0.f, 1.f - fabsf(d - 3.f));
            float w0 = ay * ax0, w1 = ay * ax1, w2 = ay * ax2, w3 = ay * ax3;
            acc0.x += fv0 * w0; acc0.y += fv1 * w0; acc0.z += fv2 * w0; acc0.w += fm * w0;
            acc1.x += fv0 * w1; acc1.y += fv1 * w1; acc1.z += fv2 * w1; acc1.w += fm * w1;
            acc2.x += fv0 * w2; acc2.y += fv1 * w2; acc2.z += fv2 * w2; acc2.w += fm * w2;
            acc3.x += fv0 * w3; acc3.y += fv1 * w3; acc3.z += fv2 * w3; acc3.w += fm * w3;
        }
    }

    const float inv0 = 1.0f / (acc0.w + EPS);
    const float inv1 = 1.0f / (acc1.w + EPS);
    const float inv2 = 1.0f / (acc2.w + EPS);
    const float inv3 = 1.0f / (acc3.w + EPS);

    const size_t pix = (size_t)gy * Ww + gx;   // gx % 4 == 0 -> 16B aligned
    float4 o;
    o = make_float4(acc0.x * inv0, acc1.x * inv1, acc2.x * inv2, acc3.x * inv3);
    *(float4*)(out + ((size_t)n * 3 + 0) * HW + pix) = o;
    o = make_float4(acc0.y * inv0, acc1.y * inv1, acc2.y * inv2, acc3.y * inv3);
    *(float4*)(out + ((size_t)n * 3 + 1) * HW + pix) = o;
    o = make_float4(acc0.z * inv0, acc1.z * inv1, acc2.z * inv2, acc3.z * inv3);
    *(float4*)(out + ((size_t)n * 3 + 2) * HW + pix) = o;
}

extern "C" void kernel_launch(void* const* d_in, const int* in_sizes, int n_in,
                              void* d_out, int out_size, void* d_ws, size_t ws_size,
                              hipStream_t stream) {
    const float* tenIn     = (const float*)d_in[0];
    const float* tenFlow   = (const float*)d_in[1];
    const float* tenMetric = (const float*)d_in[2];
    float* out = (float*)d_out;

    unsigned int* farCount = (unsigned int*)d_ws;
    float* farList = (float*)((char*)d_ws + 64);
    unsigned int farCap = (ws_size > 64) ? (unsigned int)((ws_size - 64) / 32) : 0;

    hipMemsetAsync(d_ws, 0, 64, stream);

    far_scatter<<<(TOTAL / 4 + 255) / 256, 256, 0, stream>>>(
        tenIn, tenFlow, tenMetric, farCount, farList, farCap);

    dim3 grid(TXN, TYN, Nn);
    gather_splat<<<grid, 256, 0, stream>>>(
        tenIn, tenFlow, tenMetric, farList, farCount, farCap, out);
}